// Round 1
// baseline (157.791 us; speedup 1.0000x reference)
//
#include <hip/hip_runtime.h>
#include <math.h>

#define NB 256        // batch = grid
#define N 128         // DIMX = DIMY = DIMH
#define NTHREADS 512  // 8 waves: thread = (k<<2)|h, k=0..127 row, h=0..3 K-quarter
#define MAX_IT 500

__device__ __forceinline__ float quad_sum(float p) {
    p += __shfl_xor(p, 1);
    p += __shfl_xor(p, 2);
    return p;
}
__device__ __forceinline__ float wave_sum(float p) {
    p += __shfl_xor(p, 1);
    p += __shfl_xor(p, 2);
    p += __shfl_xor(p, 4);
    p += __shfl_xor(p, 8);
    p += __shfl_xor(p, 16);
    p += __shfl_xor(p, 32);
    return p;
}
__device__ __forceinline__ float softplus_f(float s) {
    float e = __expf(-fabsf(s));
    return fmaxf(s, 0.f) + __logf(1.f + e);
}
__device__ __forceinline__ float sigmoid_f(float s) {
    float e = __expf(-fabsf(s));
    float r = 1.f / (1.f + e);
    return s >= 0.f ? r : 1.f - r;
}

// row matvec for precompute: full dot of W row k with 128-vector V (LDS),
// each lane sums its 32-quarter, quad shuffle-combine -> all 4 lanes get it.
__device__ __forceinline__ float mv_row(const float* __restrict__ W,
                                        const float* __restrict__ V,
                                        int k, int h) {
    const float4* wr = (const float4*)(W + k * N + h * 32);
    const float4* vr = (const float4*)(V + h * 32);
    float q0 = 0.f, q1 = 0.f, q2 = 0.f, q3 = 0.f;
#pragma unroll
    for (int i = 0; i < 8; ++i) {
        float4 w = wr[i], v = vr[i];
        q0 = fmaf(w.x, v.x, q0); q1 = fmaf(w.y, v.y, q1);
        q2 = fmaf(w.z, v.z, q2); q3 = fmaf(w.w, v.w, q3);
    }
    return quad_sum((q0 + q1) + (q2 + q3));
}

__global__ __launch_bounds__(NTHREADS, 2)
void picnn_solve(const float* __restrict__ x, const float* __restrict__ y,
                 const float* __restrict__ wuu0_w, const float* __restrict__ wuu0_b,
                 const float* __restrict__ wyu0_w, const float* __restrict__ wyu0_b,
                 const float* __restrict__ wy0,
                 const float* __restrict__ wu0_w, const float* __restrict__ wu0_b,
                 const float* __restrict__ wuu1_w, const float* __restrict__ wuu1_b,
                 const float* __restrict__ wzu1_w, const float* __restrict__ wzu1_b,
                 const float* __restrict__ wz1,
                 const float* __restrict__ wyu1_w, const float* __restrict__ wyu1_b,
                 const float* __restrict__ wy1,
                 const float* __restrict__ wu1_w, const float* __restrict__ wu1_b,
                 const float* __restrict__ wzu2_w, const float* __restrict__ wzu2_b,
                 const float* __restrict__ wz2,
                 const float* __restrict__ wyu2_w, const float* __restrict__ wyu2_b,
                 const float* __restrict__ wy2,
                 float* __restrict__ out)
{
    const int b = blockIdx.x;
    const int t = threadIdx.x;
    const int k = t >> 2;   // output row 0..127
    const int h = t & 3;    // K-quarter 0..3
    const int wave = t >> 6;
    const int lane = t & 63;

    __shared__ __align__(16) float xv[N];
    __shared__ __align__(16) float u0v[N];
    __shared__ __align__(16) float u1v[N];
    __shared__ __align__(16) float t0s[N];
    __shared__ __align__(16) float t2s[N];
    __shared__ __align__(16) float t1s[N];
    __shared__ __align__(16) float d2s[N];
    __shared__ __align__(16) float d1s[N];
    __shared__ float rp[8];

    if (t < N) xv[t] = x[b * N + t];
    __syncthreads();

    // ---- per-sample iteration-invariant precompute ----
    float u0k = softplus_f(mv_row(wuu0_w, xv, k, h) + wuu0_b[k]);
    float a0  = mv_row(wyu0_w, xv, k, h) + wyu0_b[k];
    float c0  = mv_row(wu0_w,  xv, k, h) + wu0_b[k];
    if (h == 0) u0v[k] = u0k;
    __syncthreads();

    float u1k = softplus_f(mv_row(wuu1_w, u0v, k, h) + wuu1_b[k]);
    float zu  = softplus_f(mv_row(wzu1_w, u0v, k, h) + wzu1_b[k]);
    float a1  = mv_row(wyu1_w, u0v, k, h) + wyu1_b[k];
    float c1  = mv_row(wu1_w,  u0v, k, h) + wu1_b[k];
    if (h == 0) u1v[k] = u1k;
    __syncthreads();

    float a2 = mv_row(wyu2_w, u1v, k, h) + wyu2_b[k];
    float e2 = a2 * wy2[k];
    float dp;
    {
        // zu2 = sp(<wzu2_w, u1>): every quad computes the same full dot
        const float4* wr = (const float4*)(wzu2_w + h * 32);
        const float4* vr = (const float4*)(u1v + h * 32);
        float q0 = 0.f, q1 = 0.f, q2 = 0.f, q3 = 0.f;
#pragma unroll
        for (int i = 0; i < 8; ++i) {
            float4 w = wr[i], v = vr[i];
            q0 = fmaf(w.x, v.x, q0); q1 = fmaf(w.y, v.y, q1);
            q2 = fmaf(w.z, v.z, q2); q3 = fmaf(w.w, v.w, q3);
        }
        float zu2 = softplus_f(quad_sum((q0 + q1) + (q2 + q3)) + wzu2_b[0]);
        dp = zu2 * fmaxf(wz2[k], 0.f);
    }

    // ---- register-resident weights: rows (forward) + cols (backward) ----
    float4 wf0[8], wf1[8], wf2[8];  // wy0 / clip(wz1) / wy1, row k, quarter h
    float4 wb0[8], wb1[8], wb2[8];  // same matrices, column k, row-quarter h
    {
        const float4* r0 = (const float4*)(wy0 + k * N + h * 32);
        const float4* r1 = (const float4*)(wz1 + k * N + h * 32);
        const float4* r2 = (const float4*)(wy1 + k * N + h * 32);
#pragma unroll
        for (int i = 0; i < 8; ++i) {
            wf0[i] = r0[i];
            float4 z = r1[i];
            z.x = fmaxf(z.x, 0.f); z.y = fmaxf(z.y, 0.f);
            z.z = fmaxf(z.z, 0.f); z.w = fmaxf(z.w, 0.f);
            wf1[i] = z;
            wf2[i] = r2[i];
        }
#pragma unroll
        for (int i = 0; i < 8; ++i) {
            int r = h * 32 + 4 * i;
            wb0[i].x = wy0[(r + 0) * N + k]; wb0[i].y = wy0[(r + 1) * N + k];
            wb0[i].z = wy0[(r + 2) * N + k]; wb0[i].w = wy0[(r + 3) * N + k];
            wb1[i].x = fmaxf(wz1[(r + 0) * N + k], 0.f);
            wb1[i].y = fmaxf(wz1[(r + 1) * N + k], 0.f);
            wb1[i].z = fmaxf(wz1[(r + 2) * N + k], 0.f);
            wb1[i].w = fmaxf(wz1[(r + 3) * N + k], 0.f);
            wb2[i].x = wy1[(r + 0) * N + k]; wb2[i].y = wy1[(r + 1) * N + k];
            wb2[i].z = wy1[(r + 2) * N + k]; wb2[i].w = wy1[(r + 3) * N + k];
        }
    }

    const float yk = y[b * N + k];
    float y1v = 1.f;
    if (h == 0) { t0s[k] = a0; t2s[k] = a1; }  // y1=1 -> t0=a0, t2=a1
    __syncthreads();

    float sig1 = 0.f;
    for (int it = 1; it <= MAX_IT; ++it) {
        // S1: s1 = t0@wy0^T + c0 ; s2a = t2@wy1^T  (fused pass over t0,t2)
        const float4* t0r = (const float4*)(t0s + h * 32);
        const float4* t2r = (const float4*)(t2s + h * 32);
        float p0 = 0.f, p1 = 0.f, p2 = 0.f, p3 = 0.f;
        float q0 = 0.f, q1 = 0.f, q2 = 0.f, q3 = 0.f;
#pragma unroll
        for (int i = 0; i < 8; ++i) {
            float4 v0 = t0r[i], v2 = t2r[i];
            p0 = fmaf(wf0[i].x, v0.x, p0); p1 = fmaf(wf0[i].y, v0.y, p1);
            p2 = fmaf(wf0[i].z, v0.z, p2); p3 = fmaf(wf0[i].w, v0.w, p3);
            q0 = fmaf(wf2[i].x, v2.x, q0); q1 = fmaf(wf2[i].y, v2.y, q1);
            q2 = fmaf(wf2[i].z, v2.z, q2); q3 = fmaf(wf2[i].w, v2.w, q3);
        }
        float s1  = quad_sum((p0 + p1) + (p2 + p3)) + c0;
        float s2a = quad_sum((q0 + q1) + (q2 + q3));
        float e1 = __expf(-fabsf(s1));
        float z1 = fmaxf(s1, 0.f) + __logf(1.f + e1);
        float rr1 = 1.f / (1.f + e1);
        sig1 = (s1 >= 0.f) ? rr1 : 1.f - rr1;
        if (h == 0) t1s[k] = z1 * zu;
        __syncthreads();

        // S2: s2 = t1@wz1c^T + s2a + c1 ; d2 = dp*sigma(s2)
        const float4* t1r = (const float4*)(t1s + h * 32);
        p0 = p1 = p2 = p3 = 0.f;
#pragma unroll
        for (int i = 0; i < 8; ++i) {
            float4 v1 = t1r[i];
            p0 = fmaf(wf1[i].x, v1.x, p0); p1 = fmaf(wf1[i].y, v1.y, p1);
            p2 = fmaf(wf1[i].z, v1.z, p2); p3 = fmaf(wf1[i].w, v1.w, p3);
        }
        float s2 = quad_sum((p0 + p1) + (p2 + p3)) + s2a + c1;
        float d2 = dp * sigmoid_f(s2);
        if (h == 0) d2s[k] = d2;
        __syncthreads();

        // S3: q = d2@wz1c (cols) ; gc = d2@wy1 (cols) ; d1 = q*zu*sig1
        const float4* d2r = (const float4*)(d2s + h * 32);
        p0 = p1 = p2 = p3 = 0.f; q0 = q1 = q2 = q3 = 0.f;
#pragma unroll
        for (int i = 0; i < 8; ++i) {
            float4 d = d2r[i];
            p0 = fmaf(wb1[i].x, d.x, p0); p1 = fmaf(wb1[i].y, d.y, p1);
            p2 = fmaf(wb1[i].z, d.z, p2); p3 = fmaf(wb1[i].w, d.w, p3);
            q0 = fmaf(wb2[i].x, d.x, q0); q1 = fmaf(wb2[i].y, d.y, q1);
            q2 = fmaf(wb2[i].z, d.z, q2); q3 = fmaf(wb2[i].w, d.w, q3);
        }
        float qv = quad_sum((p0 + p1) + (p2 + p3));
        float gc = quad_sum((q0 + q1) + (q2 + q3));
        float d1 = qv * zu * sig1;
        if (h == 0) d1s[k] = d1;
        __syncthreads();

        // S4: gb = d1@wy0 (cols); g; damped update; residual reduce
        const float4* d1r = (const float4*)(d1s + h * 32);
        p0 = p1 = p2 = p3 = 0.f;
#pragma unroll
        for (int i = 0; i < 8; ++i) {
            float4 d = d1r[i];
            p0 = fmaf(wb0[i].x, d.x, p0); p1 = fmaf(wb0[i].y, d.y, p1);
            p2 = fmaf(wb0[i].z, d.z, p2); p3 = fmaf(wb0[i].w, d.w, p3);
        }
        float gb = quad_sum((p0 + p1) + (p2 + p3));
        float g = fmaf(0.5f, y1v, e2) + gc * a1 + gb * a0;
        float rres = yk - g;
        y1v = fmaf(4.0f / (float)it, rres, y1v);
        if (h == 0) { t0s[k] = y1v * a0; t2s[k] = y1v * a1; }
        float rs = wave_sum(rres * rres);   // = 4 * sum over this wave's 16 k's
        if (lane == 0) rp[wave] = rs;
        __syncthreads();
        float tot = ((rp[0] + rp[1]) + (rp[2] + rp[3]))
                  + ((rp[4] + rp[5]) + (rp[6] + rp[7]));  // = 4*||r||^2
        if (tot < 4e-6f) break;  // per-sample ||r|| < 1e-3 (update already applied)
    }

    // out[b] = mean_k(y1 + y)
    __syncthreads();
    float v = wave_sum(y1v + yk);           // 4x duplicated per k
    if (lane == 0) rp[wave] = v;
    __syncthreads();
    if (t == 0) {
        float s = ((rp[0] + rp[1]) + (rp[2] + rp[3]))
                + ((rp[4] + rp[5]) + (rp[6] + rp[7]));
        out[b] = s * (1.f / 512.f);         // /4 duplication /128 mean
    }
}

extern "C" void kernel_launch(void* const* d_in, const int* in_sizes, int n_in,
                              void* d_out, int out_size, void* d_ws, size_t ws_size,
                              hipStream_t stream) {
    const float* x      = (const float*)d_in[0];
    const float* y      = (const float*)d_in[1];
    const float* wuu0_w = (const float*)d_in[2];
    const float* wuu0_b = (const float*)d_in[3];
    const float* wyu0_w = (const float*)d_in[4];
    const float* wyu0_b = (const float*)d_in[5];
    const float* wy0    = (const float*)d_in[6];
    const float* wu0_w  = (const float*)d_in[7];
    const float* wu0_b  = (const float*)d_in[8];
    const float* wuu1_w = (const float*)d_in[9];
    const float* wuu1_b = (const float*)d_in[10];
    const float* wzu1_w = (const float*)d_in[11];
    const float* wzu1_b = (const float*)d_in[12];
    const float* wz1    = (const float*)d_in[13];
    const float* wyu1_w = (const float*)d_in[14];
    const float* wyu1_b = (const float*)d_in[15];
    const float* wy1    = (const float*)d_in[16];
    const float* wu1_w  = (const float*)d_in[17];
    const float* wu1_b  = (const float*)d_in[18];
    const float* wzu2_w = (const float*)d_in[19];
    const float* wzu2_b = (const float*)d_in[20];
    const float* wz2    = (const float*)d_in[21];
    const float* wyu2_w = (const float*)d_in[22];
    const float* wyu2_b = (const float*)d_in[23];
    const float* wy2    = (const float*)d_in[24];
    // d_in[25]/[26] (wu2_w, wu2_b) shift the value, not the gradient -> unused
    float* out = (float*)d_out;

    picnn_solve<<<dim3(NB), dim3(NTHREADS), 0, stream>>>(
        x, y, wuu0_w, wuu0_b, wyu0_w, wyu0_b, wy0, wu0_w, wu0_b,
        wuu1_w, wuu1_b, wzu1_w, wzu1_b, wz1, wyu1_w, wyu1_b, wy1, wu1_w, wu1_b,
        wzu2_w, wzu2_b, wz2, wyu2_w, wyu2_b, wy2, out);
}

// Round 2
// 150.027 us; speedup vs baseline: 1.0518x; 1.0518x over previous
//
#include <hip/hip_runtime.h>
#include <math.h>

#define NB 256        // batch = grid
#define N 128         // DIMX = DIMY = DIMH
#define NTHREADS 512  // 8 waves: thread = (k<<2)|h, k=0..127 row, h=0..3 K-quarter
#define MAX_IT 500
// LDS vectors are stored as 4 slices of 32 floats, each slice padded to a
// 40-float stride -> slice h starts at bank 8h, so the 4 h-broadcast reads of
// a ds_read_b128 hit disjoint banks (was a 4-way conflict at stride 32).
#define SLICE 40
#define SLOT(k) ((((k) >> 5) * SLICE) + ((k) & 31))
#define LDSVEC (3 * SLICE + 32)

__device__ __forceinline__ float quad_sum(float p) {
    p += __shfl_xor(p, 1);
    p += __shfl_xor(p, 2);
    return p;
}
__device__ __forceinline__ float wave_sum(float p) {
    p += __shfl_xor(p, 1);
    p += __shfl_xor(p, 2);
    p += __shfl_xor(p, 4);
    p += __shfl_xor(p, 8);
    p += __shfl_xor(p, 16);
    p += __shfl_xor(p, 32);
    return p;
}
__device__ __forceinline__ float softplus_f(float s) {
    float e = __expf(-fabsf(s));
    return fmaxf(s, 0.f) + __logf(1.f + e);
}
__device__ __forceinline__ float sigmoid_f(float s) {
    float e = __expf(-fabsf(s));
    float r = 1.f / (1.f + e);
    return s >= 0.f ? r : 1.f - r;
}

// row matvec for precompute: dot of W row k (global) with 128-vector V (LDS,
// slice-padded layout). Each lane sums its 32-slice, quad shuffle-combine.
__device__ __forceinline__ float mv_row(const float* __restrict__ W,
                                        const float* __restrict__ V,
                                        int k, int h) {
    const float4* wr = (const float4*)(W + k * N + h * 32);
    const float4* vr = (const float4*)(V + h * SLICE);
    float q0 = 0.f, q1 = 0.f, q2 = 0.f, q3 = 0.f;
#pragma unroll
    for (int i = 0; i < 8; ++i) {
        float4 w = wr[i], v = vr[i];
        q0 = fmaf(w.x, v.x, q0); q1 = fmaf(w.y, v.y, q1);
        q2 = fmaf(w.z, v.z, q2); q3 = fmaf(w.w, v.w, q3);
    }
    return quad_sum((q0 + q1) + (q2 + q3));
}

__global__ __launch_bounds__(NTHREADS, 2)
void picnn_solve(const float* __restrict__ x, const float* __restrict__ y,
                 const float* __restrict__ wuu0_w, const float* __restrict__ wuu0_b,
                 const float* __restrict__ wyu0_w, const float* __restrict__ wyu0_b,
                 const float* __restrict__ wy0,
                 const float* __restrict__ wu0_w, const float* __restrict__ wu0_b,
                 const float* __restrict__ wuu1_w, const float* __restrict__ wuu1_b,
                 const float* __restrict__ wzu1_w, const float* __restrict__ wzu1_b,
                 const float* __restrict__ wz1,
                 const float* __restrict__ wyu1_w, const float* __restrict__ wyu1_b,
                 const float* __restrict__ wy1,
                 const float* __restrict__ wu1_w, const float* __restrict__ wu1_b,
                 const float* __restrict__ wzu2_w, const float* __restrict__ wzu2_b,
                 const float* __restrict__ wz2,
                 const float* __restrict__ wyu2_w, const float* __restrict__ wyu2_b,
                 const float* __restrict__ wy2,
                 float* __restrict__ out)
{
    const int b = blockIdx.x;
    const int t = threadIdx.x;
    const int k = t >> 2;   // output row 0..127
    const int h = t & 3;    // K-quarter 0..3
    const int wave = t >> 6;
    const int lane = t & 63;

    __shared__ __align__(16) float xv[LDSVEC];
    __shared__ __align__(16) float u0v[LDSVEC];
    __shared__ __align__(16) float u1v[LDSVEC];
    __shared__ __align__(16) float t0s[LDSVEC];
    __shared__ __align__(16) float t2s[LDSVEC];
    __shared__ __align__(16) float t1s[LDSVEC];
    __shared__ __align__(16) float d2s[LDSVEC];
    __shared__ __align__(16) float d1s[LDSVEC];
    __shared__ float rp[8];

    if (t < N) xv[SLOT(t)] = x[b * N + t];
    __syncthreads();

    // ---- per-sample iteration-invariant precompute ----
    float u0k = softplus_f(mv_row(wuu0_w, xv, k, h) + wuu0_b[k]);
    float a0  = mv_row(wyu0_w, xv, k, h) + wyu0_b[k];
    float c0  = mv_row(wu0_w,  xv, k, h) + wu0_b[k];
    if (h == 0) u0v[SLOT(k)] = u0k;
    __syncthreads();

    float u1k = softplus_f(mv_row(wuu1_w, u0v, k, h) + wuu1_b[k]);
    float zu  = softplus_f(mv_row(wzu1_w, u0v, k, h) + wzu1_b[k]);
    float a1  = mv_row(wyu1_w, u0v, k, h) + wyu1_b[k];
    float c1  = mv_row(wu1_w,  u0v, k, h) + wu1_b[k];
    if (h == 0) u1v[SLOT(k)] = u1k;
    __syncthreads();

    float a2 = mv_row(wyu2_w, u1v, k, h) + wyu2_b[k];
    float e2 = a2 * wy2[k];
    float dp;
    {
        // zu2 = sp(<wzu2_w, u1>): every quad computes the same full dot
        const float4* wr = (const float4*)(wzu2_w + h * 32);
        const float4* vr = (const float4*)(u1v + h * SLICE);
        float q0 = 0.f, q1 = 0.f, q2 = 0.f, q3 = 0.f;
#pragma unroll
        for (int i = 0; i < 8; ++i) {
            float4 w = wr[i], v = vr[i];
            q0 = fmaf(w.x, v.x, q0); q1 = fmaf(w.y, v.y, q1);
            q2 = fmaf(w.z, v.z, q2); q3 = fmaf(w.w, v.w, q3);
        }
        float zu2 = softplus_f(quad_sum((q0 + q1) + (q2 + q3)) + wzu2_b[0]);
        dp = zu2 * fmaxf(wz2[k], 0.f);
    }

    // ---- register-resident weights: rows (forward) + cols (backward) ----
    float4 wf0[8], wf1[8], wf2[8];  // wy0 / clip(wz1) / wy1, row k, quarter h
    float4 wb0[8], wb1[8], wb2[8];  // same matrices, column k, row-quarter h
    {
        const float4* r0 = (const float4*)(wy0 + k * N + h * 32);
        const float4* r1 = (const float4*)(wz1 + k * N + h * 32);
        const float4* r2 = (const float4*)(wy1 + k * N + h * 32);
#pragma unroll
        for (int i = 0; i < 8; ++i) {
            wf0[i] = r0[i];
            float4 z = r1[i];
            z.x = fmaxf(z.x, 0.f); z.y = fmaxf(z.y, 0.f);
            z.z = fmaxf(z.z, 0.f); z.w = fmaxf(z.w, 0.f);
            wf1[i] = z;
            wf2[i] = r2[i];
        }
#pragma unroll
        for (int i = 0; i < 8; ++i) {
            int r = h * 32 + 4 * i;
            wb0[i].x = wy0[(r + 0) * N + k]; wb0[i].y = wy0[(r + 1) * N + k];
            wb0[i].z = wy0[(r + 2) * N + k]; wb0[i].w = wy0[(r + 3) * N + k];
            wb1[i].x = fmaxf(wz1[(r + 0) * N + k], 0.f);
            wb1[i].y = fmaxf(wz1[(r + 1) * N + k], 0.f);
            wb1[i].z = fmaxf(wz1[(r + 2) * N + k], 0.f);
            wb1[i].w = fmaxf(wz1[(r + 3) * N + k], 0.f);
            wb2[i].x = wy1[(r + 0) * N + k]; wb2[i].y = wy1[(r + 1) * N + k];
            wb2[i].z = wy1[(r + 2) * N + k]; wb2[i].w = wy1[(r + 3) * N + k];
        }
    }

    const float yk = y[b * N + k];
    // Initial guess zeroing the linear part of the residual:
    //   g = 0.5*y1 + e2 + (small NN backprop terms)  ->  y1_0 = 2*(y - e2)
    float y1v = 2.f * (yk - e2);
    if (h == 0) { t0s[SLOT(k)] = y1v * a0; t2s[SLOT(k)] = y1v * a1; }
    __syncthreads();

    // Fixed-step gradient descent (alpha=1.25) on the 0.5-strongly-convex
    // objective; contraction <= max(0.375, |1-1.25*Lmax|). Any point with
    // ||y-g|| < 1e-3 is within 2e-3 of the reference's frozen y1 (mu=0.5),
    // far under the output threshold after dim-averaging.
    float sig1 = 0.f;
    for (int it = 1; it <= MAX_IT; ++it) {
        // S1: s1 = t0@wy0^T + c0 ; s2a = t2@wy1^T  (fused pass over t0,t2)
        const float4* t0r = (const float4*)(t0s + h * SLICE);
        const float4* t2r = (const float4*)(t2s + h * SLICE);
        float p0 = 0.f, p1 = 0.f, p2 = 0.f, p3 = 0.f;
        float q0 = 0.f, q1 = 0.f, q2 = 0.f, q3 = 0.f;
#pragma unroll
        for (int i = 0; i < 8; ++i) {
            float4 v0 = t0r[i], v2 = t2r[i];
            p0 = fmaf(wf0[i].x, v0.x, p0); p1 = fmaf(wf0[i].y, v0.y, p1);
            p2 = fmaf(wf0[i].z, v0.z, p2); p3 = fmaf(wf0[i].w, v0.w, p3);
            q0 = fmaf(wf2[i].x, v2.x, q0); q1 = fmaf(wf2[i].y, v2.y, q1);
            q2 = fmaf(wf2[i].z, v2.z, q2); q3 = fmaf(wf2[i].w, v2.w, q3);
        }
        float s1  = quad_sum((p0 + p1) + (p2 + p3)) + c0;
        float s2a = quad_sum((q0 + q1) + (q2 + q3));
        float e1 = __expf(-fabsf(s1));
        float z1 = fmaxf(s1, 0.f) + __logf(1.f + e1);
        float rr1 = 1.f / (1.f + e1);
        sig1 = (s1 >= 0.f) ? rr1 : 1.f - rr1;
        if (h == 0) t1s[SLOT(k)] = z1 * zu;
        __syncthreads();

        // S2: s2 = t1@wz1c^T + s2a + c1 ; d2 = dp*sigma(s2)
        const float4* t1r = (const float4*)(t1s + h * SLICE);
        p0 = p1 = p2 = p3 = 0.f;
#pragma unroll
        for (int i = 0; i < 8; ++i) {
            float4 v1 = t1r[i];
            p0 = fmaf(wf1[i].x, v1.x, p0); p1 = fmaf(wf1[i].y, v1.y, p1);
            p2 = fmaf(wf1[i].z, v1.z, p2); p3 = fmaf(wf1[i].w, v1.w, p3);
        }
        float s2 = quad_sum((p0 + p1) + (p2 + p3)) + s2a + c1;
        float d2 = dp * sigmoid_f(s2);
        if (h == 0) d2s[SLOT(k)] = d2;
        __syncthreads();

        // S3: q = d2@wz1c (cols) ; gc = d2@wy1 (cols) ; d1 = q*zu*sig1
        const float4* d2r = (const float4*)(d2s + h * SLICE);
        p0 = p1 = p2 = p3 = 0.f; q0 = q1 = q2 = q3 = 0.f;
#pragma unroll
        for (int i = 0; i < 8; ++i) {
            float4 d = d2r[i];
            p0 = fmaf(wb1[i].x, d.x, p0); p1 = fmaf(wb1[i].y, d.y, p1);
            p2 = fmaf(wb1[i].z, d.z, p2); p3 = fmaf(wb1[i].w, d.w, p3);
            q0 = fmaf(wb2[i].x, d.x, q0); q1 = fmaf(wb2[i].y, d.y, q1);
            q2 = fmaf(wb2[i].z, d.z, q2); q3 = fmaf(wb2[i].w, d.w, q3);
        }
        float qv = quad_sum((p0 + p1) + (p2 + p3));
        float gc = quad_sum((q0 + q1) + (q2 + q3));
        float d1 = qv * zu * sig1;
        if (h == 0) d1s[SLOT(k)] = d1;
        __syncthreads();

        // S4: gb = d1@wy0 (cols); g; fixed-step update; residual reduce
        const float4* d1r = (const float4*)(d1s + h * SLICE);
        p0 = p1 = p2 = p3 = 0.f;
#pragma unroll
        for (int i = 0; i < 8; ++i) {
            float4 d = d1r[i];
            p0 = fmaf(wb0[i].x, d.x, p0); p1 = fmaf(wb0[i].y, d.y, p1);
            p2 = fmaf(wb0[i].z, d.z, p2); p3 = fmaf(wb0[i].w, d.w, p3);
        }
        float gb = quad_sum((p0 + p1) + (p2 + p3));
        float g = fmaf(0.5f, y1v, e2) + gc * a1 + gb * a0;
        float rres = yk - g;
        y1v = fmaf(1.25f, rres, y1v);
        if (h == 0) { t0s[SLOT(k)] = y1v * a0; t2s[SLOT(k)] = y1v * a1; }
        float rs = wave_sum(rres * rres);   // = 4 * sum over this wave's 16 k's
        if (lane == 0) rp[wave] = rs;
        __syncthreads();
        float tot = ((rp[0] + rp[1]) + (rp[2] + rp[3]))
                  + ((rp[4] + rp[5]) + (rp[6] + rp[7]));  // = 4*||r||^2
        if (tot < 4e-6f) break;  // per-sample ||r|| < 1e-3 (update already applied)
    }

    // out[b] = mean_k(y1 + y)
    __syncthreads();
    float v = wave_sum(y1v + yk);           // 4x duplicated per k
    if (lane == 0) rp[wave] = v;
    __syncthreads();
    if (t == 0) {
        float s = ((rp[0] + rp[1]) + (rp[2] + rp[3]))
                + ((rp[4] + rp[5]) + (rp[6] + rp[7]));
        out[b] = s * (1.f / 512.f);         // /4 duplication /128 mean
    }
}

extern "C" void kernel_launch(void* const* d_in, const int* in_sizes, int n_in,
                              void* d_out, int out_size, void* d_ws, size_t ws_size,
                              hipStream_t stream) {
    const float* x      = (const float*)d_in[0];
    const float* y      = (const float*)d_in[1];
    const float* wuu0_w = (const float*)d_in[2];
    const float* wuu0_b = (const float*)d_in[3];
    const float* wyu0_w = (const float*)d_in[4];
    const float* wyu0_b = (const float*)d_in[5];
    const float* wy0    = (const float*)d_in[6];
    const float* wu0_w  = (const float*)d_in[7];
    const float* wu0_b  = (const float*)d_in[8];
    const float* wuu1_w = (const float*)d_in[9];
    const float* wuu1_b = (const float*)d_in[10];
    const float* wzu1_w = (const float*)d_in[11];
    const float* wzu1_b = (const float*)d_in[12];
    const float* wz1    = (const float*)d_in[13];
    const float* wyu1_w = (const float*)d_in[14];
    const float* wyu1_b = (const float*)d_in[15];
    const float* wy1    = (const float*)d_in[16];
    const float* wu1_w  = (const float*)d_in[17];
    const float* wu1_b  = (const float*)d_in[18];
    const float* wzu2_w = (const float*)d_in[19];
    const float* wzu2_b = (const float*)d_in[20];
    const float* wz2    = (const float*)d_in[21];
    const float* wyu2_w = (const float*)d_in[22];
    const float* wyu2_b = (const float*)d_in[23];
    const float* wy2    = (const float*)d_in[24];
    // d_in[25]/[26] (wu2_w, wu2_b) shift the value, not the gradient -> unused
    float* out = (float*)d_out;

    picnn_solve<<<dim3(NB), dim3(NTHREADS), 0, stream>>>(
        x, y, wuu0_w, wuu0_b, wyu0_w, wyu0_b, wy0, wu0_w, wu0_b,
        wuu1_w, wuu1_b, wzu1_w, wzu1_b, wz1, wyu1_w, wyu1_b, wy1, wu1_w, wu1_b,
        wzu2_w, wzu2_b, wz2, wyu2_w, wyu2_b, wy2, out);
}